// Round 12
// baseline (149.773 us; speedup 1.0000x reference)
//
#include <hip/hip_runtime.h>
#include <math.h>

#define TOKENS 16384
#define DIM 2048
#define NE 8
#define BLOCK 1024             // 16 waves: 0-7 gate, 8-15 noise (same 64 tokens)
#define GRID 256               // 256 blocks x 64 tokens
#define NCHUNK (DIM / 256)     // 8 chunks of 64 float4

__launch_bounds__(BLOCK, 4)   // VGPR cap 128: V[64]+xv[8] ~= 96+overhead, no spill
__global__ void router_kernel(const float* __restrict__ x,
                              const float* __restrict__ w_g,
                              const float* __restrict__ w_noise,
                              const float* __restrict__ eps,
                              float* __restrict__ out)
{
    __shared__ float wlds[16 * DIM];   // 128 KiB: rows 0..7 = w_g, 8..15 = w_noise
    __shared__ float nbuf[8][64];      // 2 KiB: noise handoff [token-octet][t*8+e]

    const int tid  = threadIdx.x;
    const int lane = tid & 63;
    const int wv   = tid >> 6;         // 0..15
    const int role = wv >> 3;          // 0: gate rows, 1: noise rows
    const int grpw = wv & 7;           // token-octet within block
    const int t0   = blockIdx.x * 64 + grpw * 8;

    const float4* x4 = (const float4*)x;

    // ---- preload chunk-0 x (latency overlaps weight staging) ----
    float4 xv[8];
    #pragma unroll
    for (int t = 0; t < 8; ++t)
        xv[t] = x4[(t0 + t) * (DIM / 4) + lane];

    // noise waves: coalesced eps — lane L gets eps for (t=L>>3, e=L&7)
    float ev = 0.f;
    if (role) ev = eps[t0 * NE + lane];

    // ---- stage weights (coalesced float4) ----
    {
        const float4* g4 = (const float4*)w_g;
        const float4* n4 = (const float4*)w_noise;
        float4* l4 = (float4*)wlds;
        #pragma unroll
        for (int i = tid; i < (NE * DIM) / 4; i += BLOCK) {
            l4[i] = g4[i];
            l4[i + (NE * DIM) / 4] = n4[i];
        }
    }
    __syncthreads();

    const float4* wl4 = (const float4*)wlds + role * (NE * DIM / 4);

    // V[t*8+r]: partial dot of row (role*8+r) with token t0+t over lane's slice
    float V[64];
    #pragma unroll
    for (int v = 0; v < 64; ++v) V[v] = 0.f;

    #pragma unroll 1                   // ROLLED: no load hoisting, no spill (R4 lesson)
    for (int k = 0; k < NCHUNK; ++k) {
        #pragma unroll
        for (int r = 0; r < 8; ++r) {
            const float4 w = wl4[r * (DIM / 4) + k * 64 + lane];
            #pragma unroll
            for (int t = 0; t < 8; ++t) {
                float a = V[t * 8 + r];
                a = fmaf(xv[t].x, w.x, a);
                a = fmaf(xv[t].y, w.y, a);
                a = fmaf(xv[t].z, w.z, a);
                a = fmaf(xv[t].w, w.w, a);
                V[t * 8 + r] = a;
            }
        }
        if (k < NCHUNK - 1) {          // use-then-refill (WAR): same regs, no 2nd buffer
            #pragma unroll
            for (int t = 0; t < 8; ++t)
                xv[t] = x4[(t0 + t) * (DIM / 4) + (k + 1) * 64 + lane];
        }
    }

    // ---- pack-halving reduction (validated): lane L ends with sum of V[L] ----
    #pragma unroll
    for (int s = 0; s < 6; ++s) {
        const int m = 1 << s;
        const int n = 64 >> s;
        #pragma unroll
        for (int j = 0; j < n / 2; ++j) {
            const float A = V[2 * j];
            const float B = V[2 * j + 1];
            const float As = __shfl_xor(A, m, 64);
            const float Bs = __shfl_xor(B, m, 64);
            V[j] = (lane & m) ? (B + Bs) : (A + As);
        }
    }
    const float mine = V[0];           // lane L: token t0+(L>>3), expert (L&7)

    if (role) {
        // stable softplus, scale by eps, hand to gate wave via LDS
        const float sp = fmaxf(mine, 0.f) + log1pf(expf(-fabsf(mine)));
        nbuf[grpw][lane] = sp * ev;
    }
    __syncthreads();
    if (!role) {
        const float logit = mine + nbuf[grpw][lane];
        const int e = lane & 7;
        const int t = lane >> 3;

        // top-2 across the 8 lanes sharing token t (e = lane bits 0..2)
        float v1 = logit, v2 = -INFINITY;
        int   i1 = e,     i2 = 7;
        #pragma unroll
        for (int sm = 0; sm <= 2; ++sm) {
            const int m = 1 << sm;
            const float ov1 = __shfl_xor(v1, m, 64);
            const float ov2 = __shfl_xor(v2, m, 64);
            const int   oi1 = __shfl_xor(i1, m, 64);
            const int   oi2 = __shfl_xor(i2, m, 64);
            // merge two (desc-value, asc-index) sorted pairs
            const bool firstA = (v1 > ov1) || (v1 == ov1 && i1 < oi1);
            const float nv1 = firstA ? v1  : ov1;
            const int   ni1 = firstA ? i1  : oi1;
            const float ca  = firstA ? ov1 : v1;    // losing head
            const int   cia = firstA ? oi1 : i1;
            const float cb  = firstA ? v2  : ov2;   // winner's second
            const int   cib = firstA ? i2  : oi2;
            const bool secondA = (ca > cb) || (ca == cb && cia < cib);
            v1 = nv1; i1 = ni1;
            v2 = secondA ? ca : cb;
            i2 = secondA ? cia : cib;
        }

        if (e == 0) {                  // 8 writer lanes: L = t*8
            const int tok = t0 + t;
            *(float2*)&out[2 * tok] = make_float2(v1, v2);
            *(float2*)&out[2 * TOKENS + 2 * tok] = make_float2((float)i1, (float)i2);
        }
    }
}

extern "C" void kernel_launch(void* const* d_in, const int* in_sizes, int n_in,
                              void* d_out, int out_size, void* d_ws, size_t ws_size,
                              hipStream_t stream) {
    const float* x       = (const float*)d_in[0];
    const float* w_g     = (const float*)d_in[1];
    const float* w_noise = (const float*)d_in[2];
    const float* eps     = (const float*)d_in[3];
    float* out = (float*)d_out;

    router_kernel<<<GRID, BLOCK, 0, stream>>>(x, w_g, w_noise, eps, out);
}

// Round 13
// 149.251 us; speedup vs baseline: 1.0035x; 1.0035x over previous
//
#include <hip/hip_runtime.h>
#include <math.h>

#define TOKENS 16384
#define DIM 2048
#define NE 8
#define BLOCK 1024             // 16 waves: 0-7 gate, 8-15 noise (same 64 tokens)
#define GRID 256               // 256 blocks x 64 tokens
#define NCHUNK (DIM / 256)     // 8 chunks of 64 float4

__launch_bounds__(BLOCK, 2)   // VGPR cap 256 (NOT 4: the (1024,4) builds twice made the
                              // allocator target 64 regs and spill V[64] -> scratch)
__global__ void router_kernel(const float* __restrict__ x,
                              const float* __restrict__ w_g,
                              const float* __restrict__ w_noise,
                              const float* __restrict__ eps,
                              float* __restrict__ out)
{
    __shared__ float wlds[16 * DIM];   // 128 KiB: rows 0..7 = w_g, 8..15 = w_noise
    __shared__ float nbuf[8][64];      // 2 KiB: noise handoff [token-octet][t*8+e]

    const int tid  = threadIdx.x;
    const int lane = tid & 63;
    const int wv   = tid >> 6;         // 0..15
    const int role = wv >> 3;          // 0: gate rows, 1: noise rows
    const int grpw = wv & 7;           // token-octet within block
    const int t0   = blockIdx.x * 64 + grpw * 8;

    const float4* x4 = (const float4*)x;

    // ---- preload chunk-0 x (latency overlaps weight staging) ----
    float4 xv[8];
    #pragma unroll
    for (int t = 0; t < 8; ++t)
        xv[t] = x4[(t0 + t) * (DIM / 4) + lane];

    // noise waves: coalesced eps — lane L gets eps for (t=L>>3, e=L&7)
    float ev = 0.f;
    if (role) ev = eps[t0 * NE + lane];

    // ---- stage weights (coalesced float4) ----
    {
        const float4* g4 = (const float4*)w_g;
        const float4* n4 = (const float4*)w_noise;
        float4* l4 = (float4*)wlds;
        #pragma unroll
        for (int i = tid; i < (NE * DIM) / 4; i += BLOCK) {
            l4[i] = g4[i];
            l4[i + (NE * DIM) / 4] = n4[i];
        }
    }
    __syncthreads();

    const float4* wl4 = (const float4*)wlds + role * (NE * DIM / 4);

    // V[t*8+r]: partial dot of row (role*8+r) with token t0+t over lane's slice
    float V[64];
    #pragma unroll
    for (int v = 0; v < 64; ++v) V[v] = 0.f;

    #pragma unroll 1                   // rolled: bound live ranges across back-edge
    for (int k = 0; k < NCHUNK; ++k) {
        #pragma unroll
        for (int r = 0; r < 8; ++r) {
            const float4 w = wl4[r * (DIM / 4) + k * 64 + lane];
            #pragma unroll
            for (int t = 0; t < 8; ++t) {
                float a = V[t * 8 + r];
                a = fmaf(xv[t].x, w.x, a);
                a = fmaf(xv[t].y, w.y, a);
                a = fmaf(xv[t].z, w.z, a);
                a = fmaf(xv[t].w, w.w, a);
                V[t * 8 + r] = a;
            }
        }
        if (k < NCHUNK - 1) {          // use-then-refill (WAR): same regs, no 2nd buffer
            #pragma unroll
            for (int t = 0; t < 8; ++t)
                xv[t] = x4[(t0 + t) * (DIM / 4) + (k + 1) * 64 + lane];
        }
    }

    // ---- pack-halving reduction (validated): lane L ends with sum of V[L] ----
    #pragma unroll
    for (int s = 0; s < 6; ++s) {
        const int m = 1 << s;
        const int n = 64 >> s;
        #pragma unroll
        for (int j = 0; j < n / 2; ++j) {
            const float A = V[2 * j];
            const float B = V[2 * j + 1];
            const float As = __shfl_xor(A, m, 64);
            const float Bs = __shfl_xor(B, m, 64);
            V[j] = (lane & m) ? (B + Bs) : (A + As);
        }
    }
    const float mine = V[0];           // lane L: token t0+(L>>3), expert (L&7)

    if (role) {
        // stable softplus, scale by eps, hand to gate wave via LDS
        const float sp = fmaxf(mine, 0.f) + log1pf(expf(-fabsf(mine)));
        nbuf[grpw][lane] = sp * ev;
    }
    __syncthreads();
    if (!role) {
        const float logit = mine + nbuf[grpw][lane];
        const int e = lane & 7;
        const int t = lane >> 3;

        // top-2 across the 8 lanes sharing token t (e = lane bits 0..2)
        float v1 = logit, v2 = -INFINITY;
        int   i1 = e,     i2 = 7;
        #pragma unroll
        for (int sm = 0; sm <= 2; ++sm) {
            const int m = 1 << sm;
            const float ov1 = __shfl_xor(v1, m, 64);
            const float ov2 = __shfl_xor(v2, m, 64);
            const int   oi1 = __shfl_xor(i1, m, 64);
            const int   oi2 = __shfl_xor(i2, m, 64);
            // merge two (desc-value, asc-index) sorted pairs
            const bool firstA = (v1 > ov1) || (v1 == ov1 && i1 < oi1);
            const float nv1 = firstA ? v1  : ov1;
            const int   ni1 = firstA ? i1  : oi1;
            const float ca  = firstA ? ov1 : v1;    // losing head
            const int   cia = firstA ? oi1 : i1;
            const float cb  = firstA ? v2  : ov2;   // winner's second
            const int   cib = firstA ? i2  : oi2;
            const bool secondA = (ca > cb) || (ca == cb && cia < cib);
            v1 = nv1; i1 = ni1;
            v2 = secondA ? ca : cb;
            i2 = secondA ? cia : cib;
        }

        if (e == 0) {                  // 8 writer lanes: L = t*8
            const int tok = t0 + t;
            *(float2*)&out[2 * tok] = make_float2(v1, v2);
            *(float2*)&out[2 * TOKENS + 2 * tok] = make_float2((float)i1, (float)i2);
        }
    }
}

extern "C" void kernel_launch(void* const* d_in, const int* in_sizes, int n_in,
                              void* d_out, int out_size, void* d_ws, size_t ws_size,
                              hipStream_t stream) {
    const float* x       = (const float*)d_in[0];
    const float* w_g     = (const float*)d_in[1];
    const float* w_noise = (const float*)d_in[2];
    const float* eps     = (const float*)d_in[3];
    float* out = (float*)d_out;

    router_kernel<<<GRID, BLOCK, 0, stream>>>(x, w_g, w_noise, eps, out);
}